// Round 1
// baseline (162.812 us; speedup 1.0000x reference)
//
#include <hip/hip_runtime.h>
#include <hip/hip_bf16.h>

typedef unsigned short u16;
typedef unsigned int u32;
typedef __attribute__((ext_vector_type(8))) short bf16x8;
typedef __attribute__((ext_vector_type(4))) float f32x4;

#define NB 4096
#define ND 512
#define NREPS (3*NB)
#define BM 128
#define BN 128
#define BK 64

__device__ __forceinline__ u16 f2bf(float f) {
  union { float f; u32 u; } v; v.f = f;
  u32 u = v.u;
  u32 r = (u + 0x7FFFu + ((u >> 16) & 1u)) >> 16;  // round-to-nearest-even
  return (u16)r;
}

// One wave per row: convert fp32 row -> bf16 into reps[3B][512], compute fp32 norm.
__global__ __launch_bounds__(64) void prep_convert(
    const float* __restrict__ ts, const float* __restrict__ i1,
    const float* __restrict__ i2, u16* __restrict__ reps,
    float* __restrict__ norms)
{
  const int row = blockIdx.x;
  const int lane = threadIdx.x;
  const float* src = (row < NB) ? (ts + (size_t)row * ND)
                   : (row < 2*NB) ? (i1 + (size_t)(row - NB) * ND)
                   : (i2 + (size_t)(row - 2*NB) * ND);
  const float4* s4 = (const float4*)src;
  float4 a = s4[lane*2+0];
  float4 b = s4[lane*2+1];
  float ss = a.x*a.x + a.y*a.y + a.z*a.z + a.w*a.w
           + b.x*b.x + b.y*b.y + b.z*b.z + b.w*b.w;
  uint4 pk;
  pk.x = (u32)f2bf(a.x) | ((u32)f2bf(a.y) << 16);
  pk.y = (u32)f2bf(a.z) | ((u32)f2bf(a.w) << 16);
  pk.z = (u32)f2bf(b.x) | ((u32)f2bf(b.y) << 16);
  pk.w = (u32)f2bf(b.z) | ((u32)f2bf(b.w) << 16);
  *(uint4*)(reps + (size_t)row * ND + lane*8) = pk;
  #pragma unroll
  for (int off = 32; off; off >>= 1) ss += __shfl_down(ss, off);
  if (lane == 0) norms[row] = ss;
}

// One wave per row: dist12 = ||img1 - img2 + eps||, and init minsq to +inf bits.
__global__ __launch_bounds__(64) void prep_dist12(
    const float* __restrict__ i1, const float* __restrict__ i2,
    float* __restrict__ dist12, u32* __restrict__ minsq)
{
  const int row = blockIdx.x;
  const int lane = threadIdx.x;
  const float4* a4 = (const float4*)(i1 + (size_t)row * ND);
  const float4* b4 = (const float4*)(i2 + (size_t)row * ND);
  float ss = 0.f;
  #pragma unroll
  for (int i = 0; i < 2; ++i) {
    float4 a = a4[lane*2+i], b = b4[lane*2+i];
    float d0 = a.x - b.x + 1e-6f, d1 = a.y - b.y + 1e-6f;
    float d2 = a.z - b.z + 1e-6f, d3 = a.w - b.w + 1e-6f;
    ss += d0*d0 + d1*d1 + d2*d2 + d3*d3;
  }
  #pragma unroll
  for (int off = 32; off; off >>= 1) ss += __shfl_down(ss, off);
  if (lane == 0) { dist12[row] = sqrtf(ss); minsq[row] = 0x7F800000u; }
}

// Fused distance-GEMM + per-row min (excluding same columns) + diagonal picks.
// C[i][j] = dot(ts_i, reps_j) via mfma_f32_16x16x32_bf16.
// 128x128 tile, BK=64, 4 waves (2x2), each wave 64x64 = 4x4 fragments.
// LDS tiles are XOR-swizzled at 16B granularity: slot ^= (row & 7).
__global__ __launch_bounds__(256) void gemm_min(
    const u16* __restrict__ reps, const float* __restrict__ norms,
    u32* __restrict__ minsq, float* __restrict__ lpos1,
    float* __restrict__ lpos2)
{
  __shared__ u16 As[BM*BK];
  __shared__ u16 Bs[BN*BK];
  const int tid  = threadIdx.x;
  const int lane = tid & 63;
  const int wave = tid >> 6;
  const int wr = wave >> 1, wc = wave & 1;
  const int fr = lane & 15, fg = lane >> 4;
  const int rowBase = blockIdx.x * BM;   // ts rows
  const int colBase = blockIdx.y * BN;   // reps rows

  f32x4 acc[4][4];
  const f32x4 zero = {0.f, 0.f, 0.f, 0.f};
  #pragma unroll
  for (int i = 0; i < 4; ++i)
    #pragma unroll
    for (int j = 0; j < 4; ++j)
      acc[i][j] = zero;

  for (int kt = 0; kt < ND/BK; ++kt) {
    const int k0 = kt * BK;
    // Stage both tiles: 1024 16B-granules each; thread takes g = i*256 + tid.
    #pragma unroll
    for (int i = 0; i < 4; ++i) {
      int g = i*256 + tid;
      int r = g >> 3, s = g & 7;
      int wslot = s ^ (r & 7);               // write-side swizzle
      uint4 va = *(const uint4*)(reps + (size_t)(rowBase + r)*ND + k0 + s*8);
      uint4 vb = *(const uint4*)(reps + (size_t)(colBase + r)*ND + k0 + s*8);
      *(uint4*)&As[r*BK + wslot*8] = va;
      *(uint4*)&Bs[r*BK + wslot*8] = vb;
    }
    __syncthreads();

    bf16x8 af[4][2], bfrag[4][2];
    #pragma unroll
    for (int mf = 0; mf < 4; ++mf)
      #pragma unroll
      for (int ks = 0; ks < 2; ++ks) {
        int rowA = wr*64 + mf*16 + fr;
        int slot = ks*4 + fg;
        af[mf][ks]    = *(const bf16x8*)&As[rowA*BK + (slot ^ (rowA & 7))*8];
        int rowB = wc*64 + mf*16 + fr;
        bfrag[mf][ks] = *(const bf16x8*)&Bs[rowB*BK + (slot ^ (rowB & 7))*8];
      }
    #pragma unroll
    for (int ks = 0; ks < 2; ++ks)
      #pragma unroll
      for (int mf = 0; mf < 4; ++mf)
        #pragma unroll
        for (int nf = 0; nf < 4; ++nf)
          acc[mf][nf] = __builtin_amdgcn_mfma_f32_16x16x32_bf16(
              af[mf][ks], bfrag[nf][ks], acc[mf][nf], 0, 0, 0);
    __syncthreads();
  }

  // Epilogue: sq = nt + nc - 2*dot; pick diagonals; row-min with exclusions.
  // C layout: col = lane&15 (fr), row = (lane>>4)*4 + q (fg,q).
  float ncol[4];
  #pragma unroll
  for (int nf = 0; nf < 4; ++nf)
    ncol[nf] = norms[colBase + wc*64 + nf*16 + fr];
  const float INF = __builtin_inff();
  #pragma unroll
  for (int mf = 0; mf < 4; ++mf) {
    #pragma unroll
    for (int q = 0; q < 4; ++q) {
      const int r_g = rowBase + wr*64 + mf*16 + fg*4 + q;
      const float ntr = norms[r_g];
      float vm = INF;
      #pragma unroll
      for (int nf = 0; nf < 4; ++nf) {
        const int c_g = colBase + wc*64 + nf*16 + fr;
        const float dot = acc[mf][nf][q];
        const float sq = ntr + ncol[nf] - 2.0f * dot;
        if (c_g == r_g + NB)   lpos1[r_g] = sq;   // unique writer
        if (c_g == r_g + 2*NB) lpos2[r_g] = sq;   // unique writer
        const bool excl = (c_g == r_g) || (c_g == r_g + NB) || (c_g == r_g + 2*NB);
        const float v = excl ? INF : fmaxf(sq, 0.0f);
        vm = fminf(vm, v);
      }
      // min across the 16 lanes holding this row's 16 columns
      #pragma unroll
      for (int off = 1; off < 16; off <<= 1)
        vm = fminf(vm, __shfl_xor(vm, off));
      if (fr == 0)
        atomicMin(minsq + r_g, __float_as_uint(vm));  // nonneg floats order as uints
    }
  }
}

__global__ __launch_bounds__(256) void finalize(
    const float* __restrict__ lpos1, const float* __restrict__ lpos2,
    const float* __restrict__ dist12, const u32* __restrict__ minsq,
    float* __restrict__ out)
{
  __shared__ float red[4];
  const int tid = threadIdx.x;
  float s = 0.f;
  for (int r = tid; r < NB; r += 256) {
    float l1 = sqrtf(fmaxf(lpos1[r], 0.f));
    float l2 = sqrtf(fmaxf(lpos2[r], 0.f));
    float neg = sqrtf(__uint_as_float(minsq[r]));   // already clamped >= 0
    float pos = l1 + l2 + dist12[r];
    float t = fmaxf(pos - neg + 0.1f, 0.f) + fmaxf(l1, l2);
    s += t;
  }
  #pragma unroll
  for (int off = 32; off; off >>= 1) s += __shfl_down(s, off);
  if ((tid & 63) == 0) red[tid >> 6] = s;
  __syncthreads();
  if (tid == 0) out[0] = (red[0] + red[1] + red[2] + red[3]) * (1.0f / NB);
}

extern "C" void kernel_launch(void* const* d_in, const int* in_sizes, int n_in,
                              void* d_out, int out_size, void* d_ws, size_t ws_size,
                              hipStream_t stream) {
  const float* ts = (const float*)d_in[0];
  const float* i1 = (const float*)d_in[1];
  const float* i2 = (const float*)d_in[2];
  float* out = (float*)d_out;

  char* p = (char*)d_ws;
  u16* reps    = (u16*)p;            p += (size_t)NREPS * ND * sizeof(u16);  // 12.6 MB
  float* norms = (float*)p;          p += (size_t)NREPS * sizeof(float);
  float* dist12 = (float*)p;         p += (size_t)NB * sizeof(float);
  u32* minsq   = (u32*)p;            p += (size_t)NB * sizeof(u32);
  float* lpos1 = (float*)p;          p += (size_t)NB * sizeof(float);
  float* lpos2 = (float*)p;          p += (size_t)NB * sizeof(float);

  prep_convert<<<NREPS, 64, 0, stream>>>(ts, i1, i2, reps, norms);
  prep_dist12<<<NB, 64, 0, stream>>>(i1, i2, dist12, minsq);
  dim3 grid(NB / BM, NREPS / BN);   // 32 x 96
  gemm_min<<<grid, 256, 0, stream>>>(reps, norms, minsq, lpos1, lpos2);
  finalize<<<1, 256, 0, stream>>>(lpos1, lpos2, dist12, minsq, out);
}

// Round 2
// 160.964 us; speedup vs baseline: 1.0115x; 1.0115x over previous
//
#include <hip/hip_runtime.h>
#include <hip/hip_bf16.h>

typedef unsigned short u16;
typedef unsigned int u32;
typedef __attribute__((ext_vector_type(8))) short bf16x8;
typedef __attribute__((ext_vector_type(4))) float f32x4;

#define NB 4096
#define ND 512
#define NREPS (3*NB)
#define BM 128
#define BN 128
#define BK 64

// global -> LDS direct DMA, 16B per lane. LDS dest is wave-uniform base +
// lane*16 (linear); swizzle is applied on the per-lane GLOBAL source addr.
#define GLD16(gp, lp)                                                         \
  __builtin_amdgcn_global_load_lds(                                           \
      (const __attribute__((address_space(1))) void*)(gp),                    \
      (__attribute__((address_space(3))) void*)(lp), 16, 0, 0)

__device__ __forceinline__ u16 f2bf(float f) {
  union { float f; u32 u; } v; v.f = f;
  u32 u = v.u;
  u32 r = (u + 0x7FFFu + ((u >> 16) & 1u)) >> 16;  // round-to-nearest-even
  return (u16)r;
}

// Fused prep: waves 0..2 convert ts/i1/i2 row r -> bf16 reps + fp32 norms;
// i1/i2 rows pass through LDS to wave 3, which computes dist12 + minsq init.
__global__ __launch_bounds__(256) void prep_all(
    const float* __restrict__ ts, const float* __restrict__ i1,
    const float* __restrict__ i2, u16* __restrict__ reps,
    float* __restrict__ norms, float* __restrict__ dist12,
    u32* __restrict__ minsq)
{
  __shared__ float s1[ND], s2[ND];
  const int r = blockIdx.x;
  const int tid = threadIdx.x;
  const int wave = tid >> 6, lane = tid & 63;

  if (wave < 3) {
    const float* src = (wave == 0) ? ts + (size_t)r * ND
                     : (wave == 1) ? i1 + (size_t)r * ND
                     :               i2 + (size_t)r * ND;
    const float4* s4 = (const float4*)src;
    float4 a = s4[lane*2+0];
    float4 b = s4[lane*2+1];
    if (wave == 1) { ((float4*)s1)[lane*2+0] = a; ((float4*)s1)[lane*2+1] = b; }
    if (wave == 2) { ((float4*)s2)[lane*2+0] = a; ((float4*)s2)[lane*2+1] = b; }
    float ss = a.x*a.x + a.y*a.y + a.z*a.z + a.w*a.w
             + b.x*b.x + b.y*b.y + b.z*b.z + b.w*b.w;
    uint4 pk;
    pk.x = (u32)f2bf(a.x) | ((u32)f2bf(a.y) << 16);
    pk.y = (u32)f2bf(a.z) | ((u32)f2bf(a.w) << 16);
    pk.z = (u32)f2bf(b.x) | ((u32)f2bf(b.y) << 16);
    pk.w = (u32)f2bf(b.z) | ((u32)f2bf(b.w) << 16);
    *(uint4*)(reps + (size_t)(wave*NB + r) * ND + lane*8) = pk;
    #pragma unroll
    for (int off = 32; off; off >>= 1) ss += __shfl_down(ss, off);
    if (lane == 0) norms[wave*NB + r] = ss;
  }
  __syncthreads();
  if (wave == 3) {
    float ss = 0.f;
    #pragma unroll
    for (int i = 0; i < 2; ++i) {
      float4 a = ((float4*)s1)[lane*2+i];
      float4 b = ((float4*)s2)[lane*2+i];
      float d0 = a.x - b.x + 1e-6f, d1 = a.y - b.y + 1e-6f;
      float d2 = a.z - b.z + 1e-6f, d3 = a.w - b.w + 1e-6f;
      ss += d0*d0 + d1*d1 + d2*d2 + d3*d3;
    }
    #pragma unroll
    for (int off = 32; off; off >>= 1) ss += __shfl_down(ss, off);
    if (lane == 0) { dist12[r] = sqrtf(ss); minsq[r] = 0x7F800000u; }
  }
}

// Fused distance-GEMM + per-row min (excluding same cols) + diagonal picks.
// 128x128 tile, BK=64, 4 waves (2x2), each wave 64x64 = 4x4 fragments.
// Staging via global_load_lds (16B/lane); LDS linear, XOR swizzle applied on
// the global source granule: LDS (row, slot') holds global granule slot'^(row&7).
__global__ __launch_bounds__(256) void gemm_min(
    const u16* __restrict__ reps, const float* __restrict__ norms,
    u32* __restrict__ minsq, float* __restrict__ lpos1,
    float* __restrict__ lpos2)
{
  __shared__ u16 As[BM*BK];
  __shared__ u16 Bs[BN*BK];
  const int tid  = threadIdx.x;
  const int lane = tid & 63;
  const int wave = tid >> 6;
  const int wr = wave >> 1, wc = wave & 1;
  const int fr = lane & 15, fg = lane >> 4;
  const int rowBase = blockIdx.x * BM;   // ts rows
  const int colBase = blockIdx.y * BN;   // reps rows

  // Per-lane global source pointers for the 4 A-chunks + 4 B-chunks this wave
  // stages each K-step. One instr covers 8 rows (64 lanes * 16B = 1 KiB).
  const int rloc = lane >> 3;      // row within 8-row chunk
  const int sp   = lane & 7;       // physical 16B slot within row
  const u16* srcA[4]; const u16* srcB[4];
  u16* dstA[4]; u16* dstB[4];
  #pragma unroll
  for (int i = 0; i < 4; ++i) {
    const int r = wave*32 + i*8 + rloc;          // tile-local row 0..127
    const int g = sp ^ (r & 7);                  // source granule (swizzled)
    srcA[i] = reps + (size_t)(rowBase + r) * ND + g*8;
    srcB[i] = reps + (size_t)(colBase + r) * ND + g*8;
    dstA[i] = &As[(wave*32 + i*8) * BK];         // wave-uniform LDS base
    dstB[i] = &Bs[(wave*32 + i*8) * BK];
  }

  f32x4 acc[4][4];
  const f32x4 zero = {0.f, 0.f, 0.f, 0.f};
  #pragma unroll
  for (int i = 0; i < 4; ++i)
    #pragma unroll
    for (int j = 0; j < 4; ++j)
      acc[i][j] = zero;

  for (int kt = 0; kt < ND/BK; ++kt) {
    const int koff = kt * BK;
    #pragma unroll
    for (int i = 0; i < 4; ++i) {
      GLD16(srcA[i] + koff, dstA[i]);
      GLD16(srcB[i] + koff, dstB[i]);
    }
    __syncthreads();   // compiler emits s_waitcnt vmcnt(0) before s_barrier

    bf16x8 af[4][2], bfrag[4][2];
    #pragma unroll
    for (int mf = 0; mf < 4; ++mf)
      #pragma unroll
      for (int ks = 0; ks < 2; ++ks) {
        const int rowA = wr*64 + mf*16 + fr;
        const int slot = ks*4 + fg;
        af[mf][ks]    = *(const bf16x8*)&As[rowA*BK + (slot ^ (rowA & 7))*8];
        const int rowB = wc*64 + mf*16 + fr;
        bfrag[mf][ks] = *(const bf16x8*)&Bs[rowB*BK + (slot ^ (rowB & 7))*8];
      }
    #pragma unroll
    for (int ks = 0; ks < 2; ++ks)
      #pragma unroll
      for (int mf = 0; mf < 4; ++mf)
        #pragma unroll
        for (int nf = 0; nf < 4; ++nf)
          acc[mf][nf] = __builtin_amdgcn_mfma_f32_16x16x32_bf16(
              af[mf][ks], bfrag[nf][ks], acc[mf][nf], 0, 0, 0);
    __syncthreads();
  }

  // Epilogue: sq = nt + nc - 2*dot; diagonal picks; row-min with exclusions.
  // C layout: col = lane&15 (fr), row = (lane>>4)*4 + q.
  float ncol[4];
  #pragma unroll
  for (int nf = 0; nf < 4; ++nf)
    ncol[nf] = norms[colBase + wc*64 + nf*16 + fr];
  const float INF = __builtin_inff();
  #pragma unroll
  for (int mf = 0; mf < 4; ++mf) {
    #pragma unroll
    for (int q = 0; q < 4; ++q) {
      const int r_g = rowBase + wr*64 + mf*16 + fg*4 + q;
      const float ntr = norms[r_g];
      float vm = INF;
      #pragma unroll
      for (int nf = 0; nf < 4; ++nf) {
        const int c_g = colBase + wc*64 + nf*16 + fr;
        const float dot = acc[mf][nf][q];
        const float sq = ntr + ncol[nf] - 2.0f * dot;
        if (c_g == r_g + NB)   lpos1[r_g] = sq;   // unique writer
        if (c_g == r_g + 2*NB) lpos2[r_g] = sq;   // unique writer
        const bool excl = (c_g == r_g) || (c_g == r_g + NB) || (c_g == r_g + 2*NB);
        const float v = excl ? INF : fmaxf(sq, 0.0f);
        vm = fminf(vm, v);
      }
      #pragma unroll
      for (int off = 1; off < 16; off <<= 1)
        vm = fminf(vm, __shfl_xor(vm, off));
      if (fr == 0)
        atomicMin(minsq + r_g, __float_as_uint(vm));  // nonneg floats order as uints
    }
  }
}

__global__ __launch_bounds__(1024) void finalize(
    const float* __restrict__ lpos1, const float* __restrict__ lpos2,
    const float* __restrict__ dist12, const u32* __restrict__ minsq,
    float* __restrict__ out)
{
  __shared__ float red[16];
  const int tid = threadIdx.x;
  float s = 0.f;
  for (int r = tid; r < NB; r += 1024) {
    float l1 = sqrtf(fmaxf(lpos1[r], 0.f));
    float l2 = sqrtf(fmaxf(lpos2[r], 0.f));
    float neg = sqrtf(__uint_as_float(minsq[r]));   // already clamped >= 0
    float pos = l1 + l2 + dist12[r];
    s += fmaxf(pos - neg + 0.1f, 0.f) + fmaxf(l1, l2);
  }
  #pragma unroll
  for (int off = 32; off; off >>= 1) s += __shfl_down(s, off);
  if ((tid & 63) == 0) red[tid >> 6] = s;
  __syncthreads();
  if (tid == 0) {
    float t = 0.f;
    #pragma unroll
    for (int i = 0; i < 16; ++i) t += red[i];
    out[0] = t * (1.0f / NB);
  }
}

extern "C" void kernel_launch(void* const* d_in, const int* in_sizes, int n_in,
                              void* d_out, int out_size, void* d_ws, size_t ws_size,
                              hipStream_t stream) {
  const float* ts = (const float*)d_in[0];
  const float* i1 = (const float*)d_in[1];
  const float* i2 = (const float*)d_in[2];
  float* out = (float*)d_out;

  char* p = (char*)d_ws;
  u16* reps    = (u16*)p;            p += (size_t)NREPS * ND * sizeof(u16);  // 12.6 MB
  float* norms = (float*)p;          p += (size_t)NREPS * sizeof(float);
  float* dist12 = (float*)p;         p += (size_t)NB * sizeof(float);
  u32* minsq   = (u32*)p;            p += (size_t)NB * sizeof(u32);
  float* lpos1 = (float*)p;          p += (size_t)NB * sizeof(float);
  float* lpos2 = (float*)p;          p += (size_t)NB * sizeof(float);

  prep_all<<<NB, 256, 0, stream>>>(ts, i1, i2, reps, norms, dist12, minsq);
  dim3 grid(NB / BM, NREPS / BN);   // 32 x 96
  gemm_min<<<grid, 256, 0, stream>>>(reps, norms, minsq, lpos1, lpos2);
  finalize<<<1, 1024, 0, stream>>>(lpos1, lpos2, dist12, minsq, out);
}